// Round 8
// baseline (185.028 us; speedup 1.0000x reference)
//
#include <hip/hip_runtime.h>
#include <hip/hip_bf16.h>
#include <cstddef>

typedef __hip_bfloat16 bf16;
typedef __attribute__((ext_vector_type(8))) short bf16x8;   // MFMA A/B frag
typedef __attribute__((ext_vector_type(4))) float f32x4;    // MFMA C/D frag
typedef __attribute__((ext_vector_type(4))) short short4v;  // 4x bf16 packed

__device__ __forceinline__ float b2f(bf16 v) { return __bfloat162float(v); }
__device__ __forceinline__ bf16 f2b(float v) { return __float2bfloat16(v); }

#define MFMA(a, b, c) __builtin_amdgcn_mfma_f32_16x16x32_bf16((a), (b), (c), 0, 0, 0)

// Weight layout inside wb (bf16): Wq [0,64K), Wkv [64K,192K), Wp [192K,256K),
// Wsr permuted [256K,512K) with k' = p*256 + c  (p = kh*2+kw).
#define WQ_OFF   0
#define WKV_OFF  65536
#define WP_OFF   196608
#define WSR_OFF  262144

// ---------------------------------------------------------------------------
// Prepass (fused): blocks [0,1024): x0|x1 fp32 -> xb bf16.
//                  blocks [1024,1536): weights fp32 -> wb bf16 (Wsr permuted).
// ---------------------------------------------------------------------------
__global__ __launch_bounds__(256) void prep_cvt(
    const float* __restrict__ x0, const float* __restrict__ x1,
    bf16* __restrict__ xb,
    const float* __restrict__ Wq, const float* __restrict__ Wkv,
    const float* __restrict__ Wp, const float* __restrict__ Wsr,
    bf16* __restrict__ wb) {
  const int t = threadIdx.x;
  if (blockIdx.x < 1024) {
    const int gid = blockIdx.x * 256 + t;             // 262144 threads
    for (int i = gid; i < 1048576; i += 262144) {     // float4 units
      const float4 v = (i < 524288) ? ((const float4*)x0)[i]
                                    : ((const float4*)x1)[i - 524288];
      union { bf16 h[4]; short4v s; } u;
      u.h[0] = f2b(v.x); u.h[1] = f2b(v.y); u.h[2] = f2b(v.z); u.h[3] = f2b(v.w);
      ((short4v*)xb)[i] = u.s;
    }
  } else {
    const int gid = (blockIdx.x - 1024) * 256 + t;    // 131072 threads
    for (int i = gid; i < 524288; i += 131072) {
      float v;
      if (i < WKV_OFF)       v = Wq[i];
      else if (i < WP_OFF)   v = Wkv[i - WKV_OFF];
      else if (i < WSR_OFF)  v = Wp[i - WP_OFF];
      else {
        const int r = i - WSR_OFF;
        const int o = r >> 10, k = r & 1023;
        const int p = k >> 8, c = k & 255;
        v = Wsr[o * 1024 + c * 4 + p];
      }
      wb[i] = f2b(v);
    }
  }
}

// W-tile staging helper: 64 rows x 256 K bf16 (32 KB) into LDS [64][264]
// (pad 264 -> 2-way-free bank reads). Coalesced 16 B per thread.
#define STAGE_W(W_lds, wgl, ldg)                                             \
  _Pragma("unroll")                                                          \
  for (int uu_ = 0; uu_ < 8; ++uu_) {                                        \
    const int idx_ = uu_ * 256 + t;                                          \
    const int wr_ = idx_ >> 5;                                               \
    const int wc_ = (idx_ & 31) * 8;                                         \
    *(bf16x8*)&W_lds[wr_][wc_] = *(const bf16x8*)((wgl) + wr_ * (ldg) + wc_);\
  }

// ---------------------------------------------------------------------------
// Kernel 2 (fused): blocks x<64:  conv as 4 p-passes of 256-K MFMA GEMM
//                                 (scheduled FIRST: long blocks, no tail).
//                   blocks x>=64: q = (xb @ Wq^T) * scale' -> bf16,
//                                 4 row-tiles per block (W staged once).
// grid (128,4) = 512 blocks, 2/CU, load-balanced (conv ~ 4x qproj unit).
// scale' folds log2(e) so attention can use raw v_exp_f32 (exp2).
// ---------------------------------------------------------------------------
__global__ __launch_bounds__(256) void qc_mfma(
    const bf16* __restrict__ xb, const bf16* __restrict__ wb,
    const float* __restrict__ bsr, bf16* __restrict__ q,
    bf16* __restrict__ xsb) {
  __shared__ bf16 W_lds[64][264];
  const int t = threadIdx.x;
  const int wave = t >> 6, lane = t & 63, quad = lane >> 4, l16 = lane & 15;
  const int colh = blockIdx.y * 64;

  if (blockIdx.x < 64) {
    // ---- conv body ----
    const int bx = blockIdx.x;
    const int row0 = bx * 64 + wave * 16;
    const int mrow = row0 + l16;
    const int ab = mrow >> 10;
    const int m = mrow & 1023;
    const int mi_ = m >> 5, mj = m & 31;
    f32x4 acc[4];
    #pragma unroll
    for (int j = 0; j < 4; ++j) acc[j] = (f32x4){0.f, 0.f, 0.f, 0.f};
    for (int p = 0; p < 4; ++p) {
      __syncthreads();   // protect previous pass's W_lds reads
      STAGE_W(W_lds, wb + WSR_OFF + colh * 1024 + p * 256, 1024);
      __syncthreads();
      const int n = (2 * mi_ + (p >> 1)) * 64 + 2 * mj + (p & 1);
      const bf16* ap = xb + (ab * 4096 + n) * 256 + quad * 8;
      #pragma unroll
      for (int c0 = 0; c0 < 256; c0 += 32) {
        const bf16x8 af = *(const bf16x8*)(ap + c0);
        #pragma unroll
        for (int j = 0; j < 4; ++j) {
          const bf16x8 wf = *(const bf16x8*)&W_lds[j * 16 + l16][c0 + quad * 8];
          acc[j] = MFMA(af, wf, acc[j]);
        }
      }
    }
    #pragma unroll
    for (int j = 0; j < 4; ++j) {
      const int col = colh + j * 16 + l16;
      const float bv = bsr[col];
      #pragma unroll
      for (int r = 0; r < 4; ++r)
        xsb[(row0 + quad * 4 + r) * 256 + col] = f2b(acc[j][r] + bv);
    }
  } else {
    // ---- q-projection body: 4 row-tiles per W stage ----
    const int idx = blockIdx.x - 64;          // 0..63
    STAGE_W(W_lds, wb + WQ_OFF + colh * 256, 256);
    __syncthreads();
    const float scale = 0.2550348572f;  // log2(e)/sqrt(32)
    for (int ii = 0; ii < 4; ++ii) {
      const int row0 = (idx * 4 + ii) * 64 + wave * 16;
      const bf16* ap = xb + (row0 + l16) * 256 + quad * 8;
      f32x4 acc[4];
      #pragma unroll
      for (int j = 0; j < 4; ++j) acc[j] = (f32x4){0.f, 0.f, 0.f, 0.f};
      #pragma unroll
      for (int k0 = 0; k0 < 256; k0 += 32) {
        const bf16x8 af = *(const bf16x8*)(ap + k0);
        #pragma unroll
        for (int j = 0; j < 4; ++j) {
          const bf16x8 wf = *(const bf16x8*)&W_lds[j * 16 + l16][k0 + quad * 8];
          acc[j] = MFMA(af, wf, acc[j]);
        }
      }
      #pragma unroll
      for (int j = 0; j < 4; ++j)
        #pragma unroll
        for (int r = 0; r < 4; ++r)
          q[(row0 + quad * 4 + r) * 256 + colh + j * 16 + l16] =
              f2b(acc[j][r] * scale);
    }
  }
}

// ---------------------------------------------------------------------------
// Kernel 3 (fused LN + kv): LayerNorm over C=256 in-register (quad-reduce
// via shfl_xor 16/32), then kv = ln(xsb) @ Wkv^T.
// K-half -> kbuf [abh][m][d]; V-half -> vbuf_t [abh][d][m'] with the bit
// permutation m' = (m&~63) | km(m&63),
//   km(j) = (j&32) | ((j&12)<<1) | ((j&16)>>2) | (j&3),
// so the swapped-QK attention's P fragments are lane-local AND its V
// fragments are directly loadable (fragment-order layout). grid (64, 8).
// ---------------------------------------------------------------------------
__global__ __launch_bounds__(256) void kvln_mfma(
    const bf16* __restrict__ xsb, const bf16* __restrict__ wb,
    const float* __restrict__ w0, const float* __restrict__ b0,
    const float* __restrict__ w1, const float* __restrict__ b1,
    bf16* __restrict__ kbuf, bf16* __restrict__ vbuf_t) {
  __shared__ bf16 W_lds[64][264];
  __shared__ float lnw[256], lnb[256];
  const int t = threadIdx.x;
  const int wave = t >> 6, lane = t & 63, quad = lane >> 4, l16 = lane & 15;
  const int row0 = blockIdx.x * 64 + wave * 16;
  const int colh = blockIdx.y * 64;     // 0..448 over O=512
  const int a = (blockIdx.x * 64) >> 11;   // block-uniform LN param select
  lnw[t] = a ? w1[t] : w0[t];
  lnb[t] = a ? b1[t] : b0[t];
  STAGE_W(W_lds, wb + WKV_OFF + colh * 256, 256);
  __syncthreads();

  const bf16* ap = xsb + (row0 + l16) * 256 + quad * 8;
  bf16x8 af[8];
  float sum = 0.f, ss = 0.f;
  #pragma unroll
  for (int i = 0; i < 8; ++i) {
    af[i] = *(const bf16x8*)(ap + i * 32);
    #pragma unroll
    for (int e = 0; e < 8; ++e) {
      const float x = b2f(((bf16*)&af[i])[e]);
      sum += x; ss += x * x;
    }
  }
  sum += __shfl_xor(sum, 16, 64); sum += __shfl_xor(sum, 32, 64);
  ss  += __shfl_xor(ss, 16, 64);  ss  += __shfl_xor(ss, 32, 64);
  const float mu = sum * (1.0f / 256.0f);
  const float var = ss * (1.0f / 256.0f) - mu * mu;
  const float rstd = rsqrtf(var + 1e-5f);
  #pragma unroll
  for (int i = 0; i < 8; ++i) {
    const int cb = i * 32 + quad * 8;
    union { bf16 h[8]; bf16x8 v; } u;
    #pragma unroll
    for (int e = 0; e < 8; ++e) {
      const float x = b2f(((bf16*)&af[i])[e]);
      u.h[e] = f2b((x - mu) * rstd * lnw[cb + e] + lnb[cb + e]);
    }
    af[i] = u.v;
  }

  f32x4 acc[4];
  #pragma unroll
  for (int j = 0; j < 4; ++j) acc[j] = (f32x4){0.f, 0.f, 0.f, 0.f};
  #pragma unroll
  for (int i = 0; i < 8; ++i) {
    #pragma unroll
    for (int j = 0; j < 4; ++j) {
      const bf16x8 wf = *(const bf16x8*)&W_lds[j * 16 + l16][i * 32 + quad * 8];
      acc[j] = MFMA(af[i], wf, acc[j]);
    }
  }
  #pragma unroll
  for (int j = 0; j < 4; ++j) {
    const int o = colh + j * 16 + l16;   // 0..511
    #pragma unroll
    for (int r = 0; r < 4; ++r) {
      const int row = row0 + quad * 4 + r;
      const int m = row & 1023;
      const bf16 val = f2b(acc[j][r]);
      if (o < 256) {
        const int h = o >> 5, d = o & 31;
        kbuf[((row >> 10) * 8 + h) * 32768 + m * 32 + d] = val;
      } else {
        const int o2 = o - 256;
        const int h = o2 >> 5, d = o2 & 31;
        const int rr = m & 63;
        const int mp = (m & ~63) | (rr & 32) | ((rr & 12) << 1) |
                       ((rr & 16) >> 2) | (rr & 3);
        vbuf_t[((row >> 10) * 8 + h) * 32768 + d * 1024 + mp] = val;
      }
    }
  }
}

// ---------------------------------------------------------------------------
// Kernel 4: MFMA flash attention, NO LDS / NO BARRIERS, register-pipelined:
//   - V fragments for iteration kt load at the TOP of the iteration and are
//     consumed after QK^T+softmax (~350 issue-cycles later).
//   - K fragments for kt+1 prefetch right after, consumed at next iter top.
// This restores the latency hiding the LDS double-buffer provided, without
// barriers or staging redundancy. Swapped QK^T (S^T = K x Q), lane-local
// in-register P. q pre-scaled by log2(e)/sqrt(d) -> raw v_exp_f32.
// ---------------------------------------------------------------------------
__global__ __launch_bounds__(256) void attn_mfma(
    const bf16* __restrict__ q, const bf16* __restrict__ kbuf,
    const bf16* __restrict__ vbuf_t, bf16* __restrict__ att) {
  const int abh = blockIdx.y;
  const int ab = abh >> 3;
  const int h = abh & 7;
  const int t = threadIdx.x;
  const int lane = t & 63, quad = lane >> 4, l16 = lane & 15;
  const int qbase = blockIdx.x * 128 + (t >> 6) * 32;

  const bf16* kb = kbuf + abh * 32768;
  const bf16* vb = vbuf_t + abh * 32768;

  bf16x8 qf[2];
  #pragma unroll
  for (int s = 0; s < 2; ++s)
    qf[s] = *(const bf16x8*)(
        q + (ab * 4096 + qbase + s * 16 + l16) * 256 + h * 32 + quad * 8);

  f32x4 o[2][2];
  float lp[2] = {0.f, 0.f};
  #pragma unroll
  for (int s = 0; s < 2; ++s) {
    o[s][0] = (f32x4){0.f, 0.f, 0.f, 0.f};
    o[s][1] = (f32x4){0.f, 0.f, 0.f, 0.f};
  }
  const f32x4 zero = {0.f, 0.f, 0.f, 0.f};

  // Per-lane base pointers (loop-invariant).
  const bf16* kfp = kb + l16 * 32 + quad * 8;    // + kt*2048 + tt*512
  const bf16* vfp = vb + l16 * 1024 + quad * 8;  // + dh*16384 + kt*64 + c2*32

  // Preload K fragments for kt=0.
  bf16x8 kfc[4];
  #pragma unroll
  for (int tt = 0; tt < 4; ++tt)
    kfc[tt] = *(const bf16x8*)(kfp + tt * 512);

  for (int kt = 0; kt < 16; ++kt) {
    // V fragments for THIS iteration: issue first, consume after softmax.
    bf16x8 vfc[4];
    #pragma unroll
    for (int i = 0; i < 4; ++i)
      vfc[i] = *(const bf16x8*)(vfp + (i >> 1) * 16384 + kt * 64 + (i & 1) * 32);
    // K fragments for NEXT iteration: issue now, consume next iter.
    bf16x8 kfn[4];
    if (kt + 1 < 16) {
      #pragma unroll
      for (int tt = 0; tt < 4; ++tt)
        kfn[tt] = *(const bf16x8*)(kfp + (kt + 1) * 2048 + tt * 512);
    }
    // S^T[key][q]: A = K-frag (current, already resident), B = Q-frag.
    f32x4 S[2][4];
    #pragma unroll
    for (int tt = 0; tt < 4; ++tt) {
      S[0][tt] = MFMA(kfc[tt], qf[0], zero);
      S[1][tt] = MFMA(kfc[tt], qf[1], zero);
    }
    // In-register softmax numerator + lane-local PV A-fragments.
    bf16x8 pa[2][2];
    #pragma unroll
    for (int s = 0; s < 2; ++s) {
      float p[4][4];
      float acc = 0.f;
      #pragma unroll
      for (int tt = 0; tt < 4; ++tt)
        #pragma unroll
        for (int r = 0; r < 4; ++r) {
          p[tt][r] = __builtin_amdgcn_exp2f(S[s][tt][r]);
          acc += p[tt][r];
        }
      lp[s] += acc;
      #pragma unroll
      for (int c2 = 0; c2 < 2; ++c2) {
        union { __hip_bfloat162 h2[4]; bf16x8 v; } u;
        u.h2[0] = __float22bfloat162_rn(float2{p[c2 * 2][0], p[c2 * 2][1]});
        u.h2[1] = __float22bfloat162_rn(float2{p[c2 * 2][2], p[c2 * 2][3]});
        u.h2[2] = __float22bfloat162_rn(float2{p[c2 * 2 + 1][0], p[c2 * 2 + 1][1]});
        u.h2[3] = __float22bfloat162_rn(float2{p[c2 * 2 + 1][2], p[c2 * 2 + 1][3]});
        pa[s][c2] = u.v;
      }
    }
    #pragma unroll
    for (int c2 = 0; c2 < 2; ++c2) {
      #pragma unroll
      for (int dh = 0; dh < 2; ++dh) {
        const bf16x8 vf = vfc[dh * 2 + c2];
        o[0][dh] = MFMA(pa[0][c2], vf, o[0][dh]);
        o[1][dh] = MFMA(pa[1][c2], vf, o[1][dh]);
      }
    }
    if (kt + 1 < 16) {
      #pragma unroll
      for (int tt = 0; tt < 4; ++tt) kfc[tt] = kfn[tt];
    }
  }
  // Denominator: sum across quads (lane ^16, ^32), broadcast, normalize.
  #pragma unroll
  for (int s = 0; s < 2; ++s) {
    lp[s] += __shfl_xor(lp[s], 16, 64);
    lp[s] += __shfl_xor(lp[s], 32, 64);
  }
  #pragma unroll
  for (int s = 0; s < 2; ++s) {
    #pragma unroll
    for (int r = 0; r < 4; ++r) {
      const float li = __shfl(lp[s], quad * 4 + r, 16);
      const float inv = 1.0f / li;
      const int qrow = ab * 4096 + qbase + s * 16 + quad * 4 + r;
      bf16* orow = att + qrow * 256 + h * 32;
      orow[l16]      = f2b(o[s][0][r] * inv);
      orow[16 + l16] = f2b(o[s][1][r] * inv);
    }
  }
}

// ---------------------------------------------------------------------------
// Kernel 5: y = att @ Wproj^T + bproj -> fp32 d_out. 2 row-tiles per W
// stage. grid (128, 4) = 512 blocks, 2/CU.
// ---------------------------------------------------------------------------
__global__ __launch_bounds__(256) void proj_mfma(
    const bf16* __restrict__ att, const bf16* __restrict__ wb,
    const float* __restrict__ bp, float* __restrict__ outp) {
  __shared__ bf16 W_lds[64][264];
  const int t = threadIdx.x;
  const int wave = t >> 6, lane = t & 63, quad = lane >> 4, l16 = lane & 15;
  const int colh = blockIdx.y * 64;
  STAGE_W(W_lds, wb + WP_OFF + colh * 256, 256);
  __syncthreads();
  for (int ii = 0; ii < 2; ++ii) {
    const int row0 = (blockIdx.x * 2 + ii) * 64 + wave * 16;
    const bf16* ap = att + (row0 + l16) * 256 + quad * 8;
    f32x4 acc[4];
    #pragma unroll
    for (int j = 0; j < 4; ++j) acc[j] = (f32x4){0.f, 0.f, 0.f, 0.f};
    #pragma unroll
    for (int k0 = 0; k0 < 256; k0 += 32) {
      const bf16x8 af = *(const bf16x8*)(ap + k0);
      #pragma unroll
      for (int j = 0; j < 4; ++j) {
        const bf16x8 wf = *(const bf16x8*)&W_lds[j * 16 + l16][k0 + quad * 8];
        acc[j] = MFMA(af, wf, acc[j]);
      }
    }
    #pragma unroll
    for (int j = 0; j < 4; ++j) {
      const int col = colh + j * 16 + l16;
      const float bv = bp[col];
      #pragma unroll
      for (int r = 0; r < 4; ++r)
        outp[(row0 + quad * 4 + r) * 256 + col] = acc[j][r] + bv;
    }
  }
}

// ---------------------------------------------------------------------------
extern "C" void kernel_launch(void* const* d_in, const int* in_sizes, int n_in,
                              void* d_out, int out_size, void* d_ws, size_t ws_size,
                              hipStream_t stream) {
  const float* x0    = (const float*)d_in[0];
  const float* x1    = (const float*)d_in[1];
  const float* Wq    = (const float*)d_in[2];
  const float* Wkv   = (const float*)d_in[3];
  const float* Wproj = (const float*)d_in[4];
  const float* bproj = (const float*)d_in[5];
  const float* Wsr   = (const float*)d_in[6];
  const float* bsr   = (const float*)d_in[7];
  const float* lnw0  = (const float*)d_in[8];
  const float* lnb0  = (const float*)d_in[9];
  const float* lnw1  = (const float*)d_in[10];
  const float* lnb1  = (const float*)d_in[11];

  // d_out (16 MB): [q bf16 8 MB][xb bf16 8 MB] -> finally y fp32 16 MB.
  // ws (15 MB): att 8 | xsb 2 | kbuf 2 | vbuf_t 2 | wb 1.
  bf16* q_bf   = (bf16*)d_out;
  bf16* xb     = q_bf + 4194304;
  bf16* att_bf = (bf16*)d_ws;
  bf16* xsb    = att_bf + 4194304;
  bf16* kbuf   = xsb + 1048576;
  bf16* vbuf_t = kbuf + 1048576;
  bf16* wb     = vbuf_t + 1048576;
  float* y     = (float*)d_out;

  const dim3 blk(256);
  prep_cvt<<<dim3(1536), blk, 0, stream>>>(x0, x1, xb, Wq, Wkv, Wproj, Wsr, wb);
  qc_mfma<<<dim3(128, 4), blk, 0, stream>>>(xb, wb, bsr, q_bf, xsb);
  kvln_mfma<<<dim3(64, 8), blk, 0, stream>>>(xsb, wb, lnw0, lnb0, lnw1, lnb1,
                                             kbuf, vbuf_t);
  attn_mfma<<<dim3(32, 32), blk, 0, stream>>>(q_bf, kbuf, vbuf_t, att_bf);
  proj_mfma<<<dim3(128, 4), blk, 0, stream>>>(att_bf, wb, bproj, y);
}

// Round 9
// 168.869 us; speedup vs baseline: 1.0957x; 1.0957x over previous
//
#include <hip/hip_runtime.h>
#include <hip/hip_bf16.h>
#include <cstddef>

typedef __hip_bfloat16 bf16;
typedef __attribute__((ext_vector_type(8))) short bf16x8;   // MFMA A/B frag
typedef __attribute__((ext_vector_type(4))) float f32x4;    // MFMA C/D frag
typedef __attribute__((ext_vector_type(4))) short short4v;  // 4x bf16 packed

__device__ __forceinline__ float b2f(bf16 v) { return __bfloat162float(v); }
__device__ __forceinline__ bf16 f2b(float v) { return __float2bfloat16(v); }

#define MFMA(a, b, c) __builtin_amdgcn_mfma_f32_16x16x32_bf16((a), (b), (c), 0, 0, 0)

// Weight layout inside wb (bf16): Wq [0,64K), Wkv [64K,192K), Wp [192K,256K),
// Wsr permuted [256K,512K) with k' = p*256 + c  (p = kh*2+kw).
#define WQ_OFF   0
#define WKV_OFF  65536
#define WP_OFF   196608
#define WSR_OFF  262144

// ---------------------------------------------------------------------------
// Prepass (fused): blocks [0,1024): x0|x1 fp32 -> xb bf16.
//                  blocks [1024,1536): weights fp32 -> wb bf16 (Wsr permuted).
// ---------------------------------------------------------------------------
__global__ __launch_bounds__(256) void prep_cvt(
    const float* __restrict__ x0, const float* __restrict__ x1,
    bf16* __restrict__ xb,
    const float* __restrict__ Wq, const float* __restrict__ Wkv,
    const float* __restrict__ Wp, const float* __restrict__ Wsr,
    bf16* __restrict__ wb) {
  const int t = threadIdx.x;
  if (blockIdx.x < 1024) {
    const int gid = blockIdx.x * 256 + t;             // 262144 threads
    for (int i = gid; i < 1048576; i += 262144) {     // float4 units
      const float4 v = (i < 524288) ? ((const float4*)x0)[i]
                                    : ((const float4*)x1)[i - 524288];
      union { bf16 h[4]; short4v s; } u;
      u.h[0] = f2b(v.x); u.h[1] = f2b(v.y); u.h[2] = f2b(v.z); u.h[3] = f2b(v.w);
      ((short4v*)xb)[i] = u.s;
    }
  } else {
    const int gid = (blockIdx.x - 1024) * 256 + t;    // 131072 threads
    for (int i = gid; i < 524288; i += 131072) {
      float v;
      if (i < WKV_OFF)       v = Wq[i];
      else if (i < WP_OFF)   v = Wkv[i - WKV_OFF];
      else if (i < WSR_OFF)  v = Wp[i - WP_OFF];
      else {
        const int r = i - WSR_OFF;
        const int o = r >> 10, k = r & 1023;
        const int p = k >> 8, c = k & 255;
        v = Wsr[o * 1024 + c * 4 + p];
      }
      wb[i] = f2b(v);
    }
  }
}

// W-tile staging helper: 64 rows x 256 K bf16 (32 KB) into LDS [64][264]
// (pad 264 -> 2-way-free bank reads). Coalesced 16 B per thread.
#define STAGE_W(W_lds, wgl, ldg)                                             \
  _Pragma("unroll")                                                          \
  for (int uu_ = 0; uu_ < 8; ++uu_) {                                        \
    const int idx_ = uu_ * 256 + t;                                          \
    const int wr_ = idx_ >> 5;                                               \
    const int wc_ = (idx_ & 31) * 8;                                         \
    *(bf16x8*)&W_lds[wr_][wc_] = *(const bf16x8*)((wgl) + wr_ * (ldg) + wc_);\
  }

// ---------------------------------------------------------------------------
// Kernel 2 (fused): blocks x<64:  conv as 4 p-passes of 256-K MFMA GEMM
//                                 (scheduled FIRST: long blocks, no tail).
//                   blocks x>=64: q = (xb @ Wq^T) * scale' -> bf16,
//                                 4 row-tiles per block (W staged once).
// grid (128,4) = 512 blocks, 2/CU, load-balanced (conv ~ 4x qproj unit).
// scale' folds log2(e) so attention can use raw v_exp_f32 (exp2).
// ---------------------------------------------------------------------------
__global__ __launch_bounds__(256) void qc_mfma(
    const bf16* __restrict__ xb, const bf16* __restrict__ wb,
    const float* __restrict__ bsr, bf16* __restrict__ q,
    bf16* __restrict__ xsb) {
  __shared__ bf16 W_lds[64][264];
  const int t = threadIdx.x;
  const int wave = t >> 6, lane = t & 63, quad = lane >> 4, l16 = lane & 15;
  const int colh = blockIdx.y * 64;

  if (blockIdx.x < 64) {
    // ---- conv body ----
    const int bx = blockIdx.x;
    const int row0 = bx * 64 + wave * 16;
    const int mrow = row0 + l16;
    const int ab = mrow >> 10;
    const int m = mrow & 1023;
    const int mi_ = m >> 5, mj = m & 31;
    f32x4 acc[4];
    #pragma unroll
    for (int j = 0; j < 4; ++j) acc[j] = (f32x4){0.f, 0.f, 0.f, 0.f};
    for (int p = 0; p < 4; ++p) {
      __syncthreads();   // protect previous pass's W_lds reads
      STAGE_W(W_lds, wb + WSR_OFF + colh * 1024 + p * 256, 1024);
      __syncthreads();
      const int n = (2 * mi_ + (p >> 1)) * 64 + 2 * mj + (p & 1);
      const bf16* ap = xb + (ab * 4096 + n) * 256 + quad * 8;
      #pragma unroll
      for (int c0 = 0; c0 < 256; c0 += 32) {
        const bf16x8 af = *(const bf16x8*)(ap + c0);
        #pragma unroll
        for (int j = 0; j < 4; ++j) {
          const bf16x8 wf = *(const bf16x8*)&W_lds[j * 16 + l16][c0 + quad * 8];
          acc[j] = MFMA(af, wf, acc[j]);
        }
      }
    }
    #pragma unroll
    for (int j = 0; j < 4; ++j) {
      const int col = colh + j * 16 + l16;
      const float bv = bsr[col];
      #pragma unroll
      for (int r = 0; r < 4; ++r)
        xsb[(row0 + quad * 4 + r) * 256 + col] = f2b(acc[j][r] + bv);
    }
  } else {
    // ---- q-projection body: 4 row-tiles per W stage ----
    const int idx = blockIdx.x - 64;          // 0..63
    STAGE_W(W_lds, wb + WQ_OFF + colh * 256, 256);
    __syncthreads();
    const float scale = 0.2550348572f;  // log2(e)/sqrt(32)
    for (int ii = 0; ii < 4; ++ii) {
      const int row0 = (idx * 4 + ii) * 64 + wave * 16;
      const bf16* ap = xb + (row0 + l16) * 256 + quad * 8;
      f32x4 acc[4];
      #pragma unroll
      for (int j = 0; j < 4; ++j) acc[j] = (f32x4){0.f, 0.f, 0.f, 0.f};
      #pragma unroll
      for (int k0 = 0; k0 < 256; k0 += 32) {
        const bf16x8 af = *(const bf16x8*)(ap + k0);
        #pragma unroll
        for (int j = 0; j < 4; ++j) {
          const bf16x8 wf = *(const bf16x8*)&W_lds[j * 16 + l16][k0 + quad * 8];
          acc[j] = MFMA(af, wf, acc[j]);
        }
      }
      #pragma unroll
      for (int j = 0; j < 4; ++j)
        #pragma unroll
        for (int r = 0; r < 4; ++r)
          q[(row0 + quad * 4 + r) * 256 + colh + j * 16 + l16] =
              f2b(acc[j][r] * scale);
    }
  }
}

// ---------------------------------------------------------------------------
// Kernel 3 (fused LN + kv): LayerNorm over C=256 in-register (quad-reduce
// via shfl_xor 16/32), then kv = ln(xsb) @ Wkv^T.
// K-half -> kbuf [abh][m][d]; V-half -> vbuf_t [abh][d][m'] with the bit
// permutation m' = (m&~63) | km(m&63),
//   km(j) = (j&32) | ((j&12)<<1) | ((j&16)>>2) | (j&3),
// so the swapped-QK attention's P fragments are lane-local AND its V
// fragments are directly loadable (fragment-order layout). grid (64, 8).
// ---------------------------------------------------------------------------
__global__ __launch_bounds__(256) void kvln_mfma(
    const bf16* __restrict__ xsb, const bf16* __restrict__ wb,
    const float* __restrict__ w0, const float* __restrict__ b0,
    const float* __restrict__ w1, const float* __restrict__ b1,
    bf16* __restrict__ kbuf, bf16* __restrict__ vbuf_t) {
  __shared__ bf16 W_lds[64][264];
  __shared__ float lnw[256], lnb[256];
  const int t = threadIdx.x;
  const int wave = t >> 6, lane = t & 63, quad = lane >> 4, l16 = lane & 15;
  const int row0 = blockIdx.x * 64 + wave * 16;
  const int colh = blockIdx.y * 64;     // 0..448 over O=512
  const int a = (blockIdx.x * 64) >> 11;   // block-uniform LN param select
  lnw[t] = a ? w1[t] : w0[t];
  lnb[t] = a ? b1[t] : b0[t];
  STAGE_W(W_lds, wb + WKV_OFF + colh * 256, 256);
  __syncthreads();

  const bf16* ap = xsb + (row0 + l16) * 256 + quad * 8;
  bf16x8 af[8];
  float sum = 0.f, ss = 0.f;
  #pragma unroll
  for (int i = 0; i < 8; ++i) {
    af[i] = *(const bf16x8*)(ap + i * 32);
    #pragma unroll
    for (int e = 0; e < 8; ++e) {
      const float x = b2f(((bf16*)&af[i])[e]);
      sum += x; ss += x * x;
    }
  }
  sum += __shfl_xor(sum, 16, 64); sum += __shfl_xor(sum, 32, 64);
  ss  += __shfl_xor(ss, 16, 64);  ss  += __shfl_xor(ss, 32, 64);
  const float mu = sum * (1.0f / 256.0f);
  const float var = ss * (1.0f / 256.0f) - mu * mu;
  const float rstd = rsqrtf(var + 1e-5f);
  #pragma unroll
  for (int i = 0; i < 8; ++i) {
    const int cb = i * 32 + quad * 8;
    union { bf16 h[8]; bf16x8 v; } u;
    #pragma unroll
    for (int e = 0; e < 8; ++e) {
      const float x = b2f(((bf16*)&af[i])[e]);
      u.h[e] = f2b((x - mu) * rstd * lnw[cb + e] + lnb[cb + e]);
    }
    af[i] = u.v;
  }

  f32x4 acc[4];
  #pragma unroll
  for (int j = 0; j < 4; ++j) acc[j] = (f32x4){0.f, 0.f, 0.f, 0.f};
  #pragma unroll
  for (int i = 0; i < 8; ++i) {
    #pragma unroll
    for (int j = 0; j < 4; ++j) {
      const bf16x8 wf = *(const bf16x8*)&W_lds[j * 16 + l16][i * 32 + quad * 8];
      acc[j] = MFMA(af[i], wf, acc[j]);
    }
  }
  #pragma unroll
  for (int j = 0; j < 4; ++j) {
    const int o = colh + j * 16 + l16;   // 0..511
    #pragma unroll
    for (int r = 0; r < 4; ++r) {
      const int row = row0 + quad * 4 + r;
      const int m = row & 1023;
      const bf16 val = f2b(acc[j][r]);
      if (o < 256) {
        const int h = o >> 5, d = o & 31;
        kbuf[((row >> 10) * 8 + h) * 32768 + m * 32 + d] = val;
      } else {
        const int o2 = o - 256;
        const int h = o2 >> 5, d = o2 & 31;
        const int rr = m & 63;
        const int mp = (m & ~63) | (rr & 32) | ((rr & 12) << 1) |
                       ((rr & 16) >> 2) | (rr & 3);
        vbuf_t[((row >> 10) * 8 + h) * 32768 + d * 1024 + mp] = val;
      }
    }
  }
}

// ---------------------------------------------------------------------------
// Kernel 4: MFMA flash attention, 512-key mega-tile LDS staging.
// Per block: stage K/V for 512 keys (64 KB LDS, single-buffered) -> barrier
// -> 8 barrier-free iterations (pure LDS + MFMA + exp) -> repeat for the
// second 512 keys. 4 barriers total (vs 16 in the per-64-key version), no
// per-iteration global prefetch, same L2 traffic (dedup via LDS).
// VT uses a symmetric XOR swizzle (col ^= (d&7)<<3 in 16B units applied on
// both reg-staged write and read) -> 2 lanes/bank (free) on PV B-reads.
// 64 KB/block -> 2 blocks/CU co-resident: one block's staging overlaps the
// other's compute. Swapped QK^T (S^T = K x Q), lane-local in-register P.
// q pre-scaled by log2(e)/sqrt(d) -> raw v_exp_f32.
// ---------------------------------------------------------------------------
__global__ __launch_bounds__(256) void attn_mfma(
    const bf16* __restrict__ q, const bf16* __restrict__ kbuf,
    const bf16* __restrict__ vbuf_t, bf16* __restrict__ att) {
  const int abh = blockIdx.y;
  const int ab = abh >> 3;
  const int h = abh & 7;
  const int t = threadIdx.x;
  const int lane = t & 63, quad = lane >> 4, l16 = lane & 15;
  const int qbase = blockIdx.x * 128 + (t >> 6) * 32;

  __shared__ bf16 KT[16384];   // 512 keys x 32 d, row-major (32 KB)
  __shared__ bf16 VT[16384];   // 32 d x 512 m', XOR-swizzled (32 KB)

  const bf16* kb = kbuf + abh * 32768;
  const bf16* vb = vbuf_t + abh * 32768;

  bf16x8 qf[2];
  #pragma unroll
  for (int s = 0; s < 2; ++s)
    qf[s] = *(const bf16x8*)(
        q + (ab * 4096 + qbase + s * 16 + l16) * 256 + h * 32 + quad * 8);

  f32x4 o[2][2];
  float lp[2] = {0.f, 0.f};
  #pragma unroll
  for (int s = 0; s < 2; ++s) {
    o[s][0] = (f32x4){0.f, 0.f, 0.f, 0.f};
    o[s][1] = (f32x4){0.f, 0.f, 0.f, 0.f};
  }
  const f32x4 zero = {0.f, 0.f, 0.f, 0.f};

  for (int half = 0; half < 2; ++half) {
    __syncthreads();   // protect previous round's LDS reads
    // ---- stage K half: linear copy, coalesced 1 KB/wave-instr ----
    #pragma unroll
    for (int u = 0; u < 8; ++u) {
      const int i = u * 256 + t;            // 2048 chunks of 16 B
      *(bf16x8*)&KT[i * 8] = *(const bf16x8*)(kb + half * 16384 + i * 8);
    }
    // ---- stage V half: per-wave d-row, XOR-swizzled LDS col ----
    #pragma unroll
    for (int u = 0; u < 8; ++u) {
      const int i = u * 256 + t;
      const int d = i >> 6;                 // 0..31 (wave-uniform)
      const int mm = (i & 63) * 8;          // 0..504
      *(bf16x8*)&VT[d * 512 + (mm ^ ((d & 7) << 3))] =
          *(const bf16x8*)(vb + d * 1024 + half * 512 + mm);
    }
    __syncthreads();

    for (int lk = 0; lk < 8; ++lk) {
      // S^T[key][q]: A = K-frag from LDS, B = Q-frag.
      f32x4 S[2][4];
      #pragma unroll
      for (int tt = 0; tt < 4; ++tt) {
        const bf16x8 kf =
            *(const bf16x8*)&KT[(lk * 64 + tt * 16 + l16) * 32 + quad * 8];
        S[0][tt] = MFMA(kf, qf[0], zero);
        S[1][tt] = MFMA(kf, qf[1], zero);
      }
      // In-register softmax numerator + lane-local PV A-fragments.
      bf16x8 pa[2][2];
      #pragma unroll
      for (int s = 0; s < 2; ++s) {
        float p[4][4];
        float acc = 0.f;
        #pragma unroll
        for (int tt = 0; tt < 4; ++tt)
          #pragma unroll
          for (int r = 0; r < 4; ++r) {
            p[tt][r] = __builtin_amdgcn_exp2f(S[s][tt][r]);
            acc += p[tt][r];
          }
        lp[s] += acc;
        #pragma unroll
        for (int c2 = 0; c2 < 2; ++c2) {
          union { __hip_bfloat162 h2[4]; bf16x8 v; } u;
          u.h2[0] = __float22bfloat162_rn(float2{p[c2 * 2][0], p[c2 * 2][1]});
          u.h2[1] = __float22bfloat162_rn(float2{p[c2 * 2][2], p[c2 * 2][3]});
          u.h2[2] = __float22bfloat162_rn(float2{p[c2 * 2 + 1][0], p[c2 * 2 + 1][1]});
          u.h2[3] = __float22bfloat162_rn(float2{p[c2 * 2 + 1][2], p[c2 * 2 + 1][3]});
          pa[s][c2] = u.v;
        }
      }
      #pragma unroll
      for (int c2 = 0; c2 < 2; ++c2) {
        #pragma unroll
        for (int dh = 0; dh < 2; ++dh) {
          const int d = l16 + dh * 16;
          const int mm = lk * 64 + c2 * 32 + quad * 8;
          const bf16x8 vf =
              *(const bf16x8*)&VT[d * 512 + (mm ^ ((d & 7) << 3))];
          o[0][dh] = MFMA(pa[0][c2], vf, o[0][dh]);
          o[1][dh] = MFMA(pa[1][c2], vf, o[1][dh]);
        }
      }
    }
  }
  // Denominator: sum across quads (lane ^16, ^32), broadcast, normalize.
  #pragma unroll
  for (int s = 0; s < 2; ++s) {
    lp[s] += __shfl_xor(lp[s], 16, 64);
    lp[s] += __shfl_xor(lp[s], 32, 64);
  }
  #pragma unroll
  for (int s = 0; s < 2; ++s) {
    #pragma unroll
    for (int r = 0; r < 4; ++r) {
      const float li = __shfl(lp[s], quad * 4 + r, 16);
      const float inv = 1.0f / li;
      const int qrow = ab * 4096 + qbase + s * 16 + quad * 4 + r;
      bf16* orow = att + qrow * 256 + h * 32;
      orow[l16]      = f2b(o[s][0][r] * inv);
      orow[16 + l16] = f2b(o[s][1][r] * inv);
    }
  }
}

// ---------------------------------------------------------------------------
// Kernel 5: y = att @ Wproj^T + bproj -> fp32 d_out. 2 row-tiles per W
// stage. grid (128, 4) = 512 blocks, 2/CU.
// ---------------------------------------------------------------------------
__global__ __launch_bounds__(256) void proj_mfma(
    const bf16* __restrict__ att, const bf16* __restrict__ wb,
    const float* __restrict__ bp, float* __restrict__ outp) {
  __shared__ bf16 W_lds[64][264];
  const int t = threadIdx.x;
  const int wave = t >> 6, lane = t & 63, quad = lane >> 4, l16 = lane & 15;
  const int colh = blockIdx.y * 64;
  STAGE_W(W_lds, wb + WP_OFF + colh * 256, 256);
  __syncthreads();
  for (int ii = 0; ii < 2; ++ii) {
    const int row0 = (blockIdx.x * 2 + ii) * 64 + wave * 16;
    const bf16* ap = att + (row0 + l16) * 256 + quad * 8;
    f32x4 acc[4];
    #pragma unroll
    for (int j = 0; j < 4; ++j) acc[j] = (f32x4){0.f, 0.f, 0.f, 0.f};
    #pragma unroll
    for (int k0 = 0; k0 < 256; k0 += 32) {
      const bf16x8 af = *(const bf16x8*)(ap + k0);
      #pragma unroll
      for (int j = 0; j < 4; ++j) {
        const bf16x8 wf = *(const bf16x8*)&W_lds[j * 16 + l16][k0 + quad * 8];
        acc[j] = MFMA(af, wf, acc[j]);
      }
    }
    #pragma unroll
    for (int j = 0; j < 4; ++j) {
      const int col = colh + j * 16 + l16;
      const float bv = bp[col];
      #pragma unroll
      for (int r = 0; r < 4; ++r)
        outp[(row0 + quad * 4 + r) * 256 + col] = acc[j][r] + bv;
    }
  }
}

// ---------------------------------------------------------------------------
extern "C" void kernel_launch(void* const* d_in, const int* in_sizes, int n_in,
                              void* d_out, int out_size, void* d_ws, size_t ws_size,
                              hipStream_t stream) {
  const float* x0    = (const float*)d_in[0];
  const float* x1    = (const float*)d_in[1];
  const float* Wq    = (const float*)d_in[2];
  const float* Wkv   = (const float*)d_in[3];
  const float* Wproj = (const float*)d_in[4];
  const float* bproj = (const float*)d_in[5];
  const float* Wsr   = (const float*)d_in[6];
  const float* bsr   = (const float*)d_in[7];
  const float* lnw0  = (const float*)d_in[8];
  const float* lnb0  = (const float*)d_in[9];
  const float* lnw1  = (const float*)d_in[10];
  const float* lnb1  = (const float*)d_in[11];

  // d_out (16 MB): [q bf16 8 MB][xb bf16 8 MB] -> finally y fp32 16 MB.
  // ws (15 MB): att 8 | xsb 2 | kbuf 2 | vbuf_t 2 | wb 1.
  bf16* q_bf   = (bf16*)d_out;
  bf16* xb     = q_bf + 4194304;
  bf16* att_bf = (bf16*)d_ws;
  bf16* xsb    = att_bf + 4194304;
  bf16* kbuf   = xsb + 1048576;
  bf16* vbuf_t = kbuf + 1048576;
  bf16* wb     = vbuf_t + 1048576;
  float* y     = (float*)d_out;

  const dim3 blk(256);
  prep_cvt<<<dim3(1536), blk, 0, stream>>>(x0, x1, xb, Wq, Wkv, Wproj, Wsr, wb);
  qc_mfma<<<dim3(128, 4), blk, 0, stream>>>(xb, wb, bsr, q_bf, xsb);
  kvln_mfma<<<dim3(64, 8), blk, 0, stream>>>(xsb, wb, lnw0, lnb0, lnw1, lnb1,
                                             kbuf, vbuf_t);
  attn_mfma<<<dim3(32, 32), blk, 0, stream>>>(q_bf, kbuf, vbuf_t, att_bf);
  proj_mfma<<<dim3(128, 4), blk, 0, stream>>>(att_bf, wb, bproj, y);
}

// Round 10
// 155.715 us; speedup vs baseline: 1.1882x; 1.0845x over previous
//
#include <hip/hip_runtime.h>
#include <hip/hip_bf16.h>
#include <cstddef>

typedef __hip_bfloat16 bf16;
typedef __attribute__((ext_vector_type(8))) short bf16x8;   // MFMA A/B frag
typedef __attribute__((ext_vector_type(4))) float f32x4;    // MFMA C/D frag
typedef __attribute__((ext_vector_type(4))) short short4v;  // 4x bf16 packed

__device__ __forceinline__ float b2f(bf16 v) { return __bfloat162float(v); }
__device__ __forceinline__ bf16 f2b(float v) { return __float2bfloat16(v); }

#define MFMA(a, b, c) __builtin_amdgcn_mfma_f32_16x16x32_bf16((a), (b), (c), 0, 0, 0)

// Weight layout inside wb (bf16): Wq [0,64K), Wkv [64K,192K), Wp [192K,256K),
// Wsr permuted [256K,512K) with k' = p*256 + c  (p = kh*2+kw).
#define WQ_OFF   0
#define WKV_OFF  65536
#define WP_OFF   196608
#define WSR_OFF  262144

// ---------------------------------------------------------------------------
// Prepass (fused): blocks [0,1024): x0|x1 fp32 -> xb bf16.
//                  blocks [1024,1536): weights fp32 -> wb bf16 (Wsr permuted).
// ---------------------------------------------------------------------------
__global__ __launch_bounds__(256) void prep_cvt(
    const float* __restrict__ x0, const float* __restrict__ x1,
    bf16* __restrict__ xb,
    const float* __restrict__ Wq, const float* __restrict__ Wkv,
    const float* __restrict__ Wp, const float* __restrict__ Wsr,
    bf16* __restrict__ wb) {
  const int t = threadIdx.x;
  if (blockIdx.x < 1024) {
    const int gid = blockIdx.x * 256 + t;             // 262144 threads
    for (int i = gid; i < 1048576; i += 262144) {     // float4 units
      const float4 v = (i < 524288) ? ((const float4*)x0)[i]
                                    : ((const float4*)x1)[i - 524288];
      union { bf16 h[4]; short4v s; } u;
      u.h[0] = f2b(v.x); u.h[1] = f2b(v.y); u.h[2] = f2b(v.z); u.h[3] = f2b(v.w);
      ((short4v*)xb)[i] = u.s;
    }
  } else {
    const int gid = (blockIdx.x - 1024) * 256 + t;    // 131072 threads
    for (int i = gid; i < 524288; i += 131072) {
      float v;
      if (i < WKV_OFF)       v = Wq[i];
      else if (i < WP_OFF)   v = Wkv[i - WKV_OFF];
      else if (i < WSR_OFF)  v = Wp[i - WP_OFF];
      else {
        const int r = i - WSR_OFF;
        const int o = r >> 10, k = r & 1023;
        const int p = k >> 8, c = k & 255;
        v = Wsr[o * 1024 + c * 4 + p];
      }
      wb[i] = f2b(v);
    }
  }
}

// W-tile staging helper: 64 rows x 256 K bf16 (32 KB) into LDS [64][264]
// (pad 264 -> 2-way-free bank reads). Coalesced 16 B per thread.
#define STAGE_W(W_lds, wgl, ldg)                                             \
  _Pragma("unroll")                                                          \
  for (int uu_ = 0; uu_ < 8; ++uu_) {                                        \
    const int idx_ = uu_ * 256 + t;                                          \
    const int wr_ = idx_ >> 5;                                               \
    const int wc_ = (idx_ & 31) * 8;                                         \
    *(bf16x8*)&W_lds[wr_][wc_] = *(const bf16x8*)((wgl) + wr_ * (ldg) + wc_);\
  }

// ---------------------------------------------------------------------------
// Kernel 2 (fused): blocks x<64:  conv as 4 p-passes of 256-K MFMA GEMM
//                                 (scheduled FIRST: long blocks, no tail).
//                   blocks x>=64: q = (xb @ Wq^T) * scale' -> bf16.
//   qproj is k0-OUTER over 4 concurrent row-tiles: per K-step, 4 A-frag
//   global loads + 4 W-frag LDS reads feed 16 MFMA (reads/MFMA 1.25->0.5;
//   4 independent A loads per step give memory-level parallelism).
// grid (128,4) = 512 blocks, 2/CU. scale' folds log2(e) -> raw v_exp_f32.
// ---------------------------------------------------------------------------
__global__ __launch_bounds__(256) void qc_mfma(
    const bf16* __restrict__ xb, const bf16* __restrict__ wb,
    const float* __restrict__ bsr, bf16* __restrict__ q,
    bf16* __restrict__ xsb) {
  __shared__ bf16 W_lds[64][264];
  const int t = threadIdx.x;
  const int wave = t >> 6, lane = t & 63, quad = lane >> 4, l16 = lane & 15;
  const int colh = blockIdx.y * 64;

  if (blockIdx.x < 64) {
    // ---- conv body (unchanged) ----
    const int bx = blockIdx.x;
    const int row0 = bx * 64 + wave * 16;
    const int mrow = row0 + l16;
    const int ab = mrow >> 10;
    const int m = mrow & 1023;
    const int mi_ = m >> 5, mj = m & 31;
    f32x4 acc[4];
    #pragma unroll
    for (int j = 0; j < 4; ++j) acc[j] = (f32x4){0.f, 0.f, 0.f, 0.f};
    for (int p = 0; p < 4; ++p) {
      __syncthreads();   // protect previous pass's W_lds reads
      STAGE_W(W_lds, wb + WSR_OFF + colh * 1024 + p * 256, 1024);
      __syncthreads();
      const int n = (2 * mi_ + (p >> 1)) * 64 + 2 * mj + (p & 1);
      const bf16* ap = xb + (ab * 4096 + n) * 256 + quad * 8;
      #pragma unroll
      for (int c0 = 0; c0 < 256; c0 += 32) {
        const bf16x8 af = *(const bf16x8*)(ap + c0);
        #pragma unroll
        for (int j = 0; j < 4; ++j) {
          const bf16x8 wf = *(const bf16x8*)&W_lds[j * 16 + l16][c0 + quad * 8];
          acc[j] = MFMA(af, wf, acc[j]);
        }
      }
    }
    #pragma unroll
    for (int j = 0; j < 4; ++j) {
      const int col = colh + j * 16 + l16;
      const float bv = bsr[col];
      #pragma unroll
      for (int r = 0; r < 4; ++r)
        xsb[(row0 + quad * 4 + r) * 256 + col] = f2b(acc[j][r] + bv);
    }
  } else {
    // ---- q-projection: 4 row-tiles concurrent, k0-outer ----
    const int idx = blockIdx.x - 64;          // 0..63
    STAGE_W(W_lds, wb + WQ_OFF + colh * 256, 256);
    __syncthreads();
    const bf16* ap0 =
        xb + ((idx * 4) * 64 + wave * 16 + l16) * 256 + quad * 8;
    f32x4 acc[4][4];                          // [row-tile ii][col j]
    #pragma unroll
    for (int ii = 0; ii < 4; ++ii)
      #pragma unroll
      for (int j = 0; j < 4; ++j) acc[ii][j] = (f32x4){0.f, 0.f, 0.f, 0.f};
    #pragma unroll
    for (int k0 = 0; k0 < 256; k0 += 32) {
      bf16x8 af[4];
      #pragma unroll
      for (int ii = 0; ii < 4; ++ii)
        af[ii] = *(const bf16x8*)(ap0 + ii * 16384 + k0);   // +64 rows each
      #pragma unroll
      for (int j = 0; j < 4; ++j) {
        const bf16x8 wf = *(const bf16x8*)&W_lds[j * 16 + l16][k0 + quad * 8];
        #pragma unroll
        for (int ii = 0; ii < 4; ++ii)
          acc[ii][j] = MFMA(af[ii], wf, acc[ii][j]);
      }
    }
    const float scale = 0.2550348572f;  // log2(e)/sqrt(32)
    #pragma unroll
    for (int ii = 0; ii < 4; ++ii) {
      const int row0 = (idx * 4 + ii) * 64 + wave * 16;
      #pragma unroll
      for (int j = 0; j < 4; ++j)
        #pragma unroll
        for (int r = 0; r < 4; ++r)
          q[(row0 + quad * 4 + r) * 256 + colh + j * 16 + l16] =
              f2b(acc[ii][j][r] * scale);
    }
  }
}

// ---------------------------------------------------------------------------
// Kernel 3 (fused LN + kv): LayerNorm over C=256 in-register (quad-reduce
// via shfl_xor 16/32), then kv = ln(xsb) @ Wkv^T.
// K-half -> kbuf [abh][m][d]; V-half -> vbuf_t [abh][d][m'] with the bit
// permutation m' = (m&~63) | km(m&63),
//   km(j) = (j&32) | ((j&12)<<1) | ((j&16)>>2) | (j&3),
// so the swapped-QK attention's P fragments are lane-local. grid (64, 8).
// ---------------------------------------------------------------------------
__global__ __launch_bounds__(256) void kvln_mfma(
    const bf16* __restrict__ xsb, const bf16* __restrict__ wb,
    const float* __restrict__ w0, const float* __restrict__ b0,
    const float* __restrict__ w1, const float* __restrict__ b1,
    bf16* __restrict__ kbuf, bf16* __restrict__ vbuf_t) {
  __shared__ bf16 W_lds[64][264];
  __shared__ float lnw[256], lnb[256];
  const int t = threadIdx.x;
  const int wave = t >> 6, lane = t & 63, quad = lane >> 4, l16 = lane & 15;
  const int row0 = blockIdx.x * 64 + wave * 16;
  const int colh = blockIdx.y * 64;     // 0..448 over O=512
  const int a = (blockIdx.x * 64) >> 11;   // block-uniform LN param select
  lnw[t] = a ? w1[t] : w0[t];
  lnb[t] = a ? b1[t] : b0[t];
  STAGE_W(W_lds, wb + WKV_OFF + colh * 256, 256);
  __syncthreads();

  const bf16* ap = xsb + (row0 + l16) * 256 + quad * 8;
  bf16x8 af[8];
  float sum = 0.f, ss = 0.f;
  #pragma unroll
  for (int i = 0; i < 8; ++i) {
    af[i] = *(const bf16x8*)(ap + i * 32);
    #pragma unroll
    for (int e = 0; e < 8; ++e) {
      const float x = b2f(((bf16*)&af[i])[e]);
      sum += x; ss += x * x;
    }
  }
  sum += __shfl_xor(sum, 16, 64); sum += __shfl_xor(sum, 32, 64);
  ss  += __shfl_xor(ss, 16, 64);  ss  += __shfl_xor(ss, 32, 64);
  const float mu = sum * (1.0f / 256.0f);
  const float var = ss * (1.0f / 256.0f) - mu * mu;
  const float rstd = rsqrtf(var + 1e-5f);
  #pragma unroll
  for (int i = 0; i < 8; ++i) {
    const int cb = i * 32 + quad * 8;
    union { bf16 h[8]; bf16x8 v; } u;
    #pragma unroll
    for (int e = 0; e < 8; ++e) {
      const float x = b2f(((bf16*)&af[i])[e]);
      u.h[e] = f2b((x - mu) * rstd * lnw[cb + e] + lnb[cb + e]);
    }
    af[i] = u.v;
  }

  f32x4 acc[4];
  #pragma unroll
  for (int j = 0; j < 4; ++j) acc[j] = (f32x4){0.f, 0.f, 0.f, 0.f};
  #pragma unroll
  for (int i = 0; i < 8; ++i) {
    #pragma unroll
    for (int j = 0; j < 4; ++j) {
      const bf16x8 wf = *(const bf16x8*)&W_lds[j * 16 + l16][i * 32 + quad * 8];
      acc[j] = MFMA(af[i], wf, acc[j]);
    }
  }
  #pragma unroll
  for (int j = 0; j < 4; ++j) {
    const int o = colh + j * 16 + l16;   // 0..511
    #pragma unroll
    for (int r = 0; r < 4; ++r) {
      const int row = row0 + quad * 4 + r;
      const int m = row & 1023;
      const bf16 val = f2b(acc[j][r]);
      if (o < 256) {
        const int h = o >> 5, d = o & 31;
        kbuf[((row >> 10) * 8 + h) * 32768 + m * 32 + d] = val;
      } else {
        const int o2 = o - 256;
        const int h = o2 >> 5, d = o2 & 31;
        const int rr = m & 63;
        const int mp = (m & ~63) | (rr & 32) | ((rr & 12) << 1) |
                       ((rr & 16) >> 2) | (rr & 3);
        vbuf_t[((row >> 10) * 8 + h) * 32768 + d * 1024 + mp] = val;
      }
    }
  }
}

// ---------------------------------------------------------------------------
// Kernel 4: MFMA flash attention — the PROVEN round-2/6 structure verbatim:
// LDS-staged K/V, double-buffered, per-64-key tiles, swapped QK^T
// (S^T = K x Q) with lane-local in-register P -> PV fragments.
// q pre-scaled by log2(e)/sqrt(d) -> raw v_exp_f32. Best of 4 measured
// attention structures (34.5 vs 44.8/54.8/62.4 us).
// ---------------------------------------------------------------------------
__global__ __launch_bounds__(256) void attn_mfma(
    const bf16* __restrict__ q, const bf16* __restrict__ kbuf,
    const bf16* __restrict__ vbuf_t, bf16* __restrict__ att) {
  const int abh = blockIdx.y;
  const int ab = abh >> 3;
  const int h = abh & 7;
  const int t = threadIdx.x;
  const int lane = t & 63, quad = lane >> 4, l16 = lane & 15;
  const int qbase = blockIdx.x * 128 + (t >> 6) * 32;

  __shared__ bf16 KT[2][2048];
  __shared__ bf16 VT[2][2048];

  const bf16* kb = kbuf + abh * 32768;
  const bf16* vb = vbuf_t + abh * 32768;

  const int kg = (t >> 6) * 512 + ((t >> 2) & 15) * 32 + (t & 3) * 8;
  const int vg_row = (t >> 7) * 16 + ((t >> 3) & 15);
  const int vg_col = ((t >> 2) & 1) * 32 + (t & 3) * 8;

  bf16x8 qf[2];
  #pragma unroll
  for (int s = 0; s < 2; ++s)
    qf[s] = *(const bf16x8*)(
        q + (ab * 4096 + qbase + s * 16 + l16) * 256 + h * 32 + quad * 8);

  {
    const bf16x8 kr = *(const bf16x8*)(kb + kg);
    const bf16x8 vr = *(const bf16x8*)(vb + vg_row * 1024 + vg_col);
    *(bf16x8*)&KT[0][t * 8] = kr;
    *(bf16x8*)&VT[0][t * 8] = vr;
  }
  __syncthreads();

  f32x4 o[2][2];
  float lp[2] = {0.f, 0.f};
  #pragma unroll
  for (int s = 0; s < 2; ++s) {
    o[s][0] = (f32x4){0.f, 0.f, 0.f, 0.f};
    o[s][1] = (f32x4){0.f, 0.f, 0.f, 0.f};
  }
  const f32x4 zero = {0.f, 0.f, 0.f, 0.f};

  for (int kt = 0; kt < 16; ++kt) {
    const int cur = kt & 1;
    bf16x8 kr, vr;
    const bool pf = (kt + 1 < 16);
    if (pf) {
      const int nk0 = (kt + 1) * 64;
      kr = *(const bf16x8*)(kb + nk0 * 32 + kg);
      vr = *(const bf16x8*)(vb + vg_row * 1024 + nk0 + vg_col);
    }
    // S^T[key][q]: A = K-frag (row=key), B = Q-frag (col=q=l16).
    f32x4 S[2][4];
    #pragma unroll
    for (int tt = 0; tt < 4; ++tt) {
      const bf16x8 kf =
          *(const bf16x8*)&KT[cur][(tt * 64 + l16 * 4 + quad) * 8];
      S[0][tt] = MFMA(kf, qf[0], zero);
      S[1][tt] = MFMA(kf, qf[1], zero);
    }
    // In-register softmax numerator + lane-local PV A-fragments.
    bf16x8 pa[2][2];
    #pragma unroll
    for (int s = 0; s < 2; ++s) {
      float p[4][4];
      float acc = 0.f;
      #pragma unroll
      for (int tt = 0; tt < 4; ++tt)
        #pragma unroll
        for (int r = 0; r < 4; ++r) {
          p[tt][r] = __builtin_amdgcn_exp2f(S[s][tt][r]);
          acc += p[tt][r];
        }
      lp[s] += acc;
      #pragma unroll
      for (int c2 = 0; c2 < 2; ++c2) {
        union { __hip_bfloat162 h2[4]; bf16x8 v; } u;
        u.h2[0] = __float22bfloat162_rn(float2{p[c2 * 2][0], p[c2 * 2][1]});
        u.h2[1] = __float22bfloat162_rn(float2{p[c2 * 2][2], p[c2 * 2][3]});
        u.h2[2] = __float22bfloat162_rn(float2{p[c2 * 2 + 1][0], p[c2 * 2 + 1][1]});
        u.h2[3] = __float22bfloat162_rn(float2{p[c2 * 2 + 1][2], p[c2 * 2 + 1][3]});
        pa[s][c2] = u.v;
      }
    }
    #pragma unroll
    for (int c2 = 0; c2 < 2; ++c2) {
      #pragma unroll
      for (int dh = 0; dh < 2; ++dh) {
        const bf16x8 vf = *(const bf16x8*)&VT[cur]
            [(dh * 128 + l16 * 8 + c2 * 4 + quad) * 8];
        o[0][dh] = MFMA(pa[0][c2], vf, o[0][dh]);
        o[1][dh] = MFMA(pa[1][c2], vf, o[1][dh]);
      }
    }
    if (pf) {
      *(bf16x8*)&KT[cur ^ 1][t * 8] = kr;
      *(bf16x8*)&VT[cur ^ 1][t * 8] = vr;
    }
    __syncthreads();
  }
  // Denominator: sum across quads (lane ^16, ^32), broadcast, normalize.
  #pragma unroll
  for (int s = 0; s < 2; ++s) {
    lp[s] += __shfl_xor(lp[s], 16, 64);
    lp[s] += __shfl_xor(lp[s], 32, 64);
  }
  #pragma unroll
  for (int s = 0; s < 2; ++s) {
    #pragma unroll
    for (int r = 0; r < 4; ++r) {
      const float li = __shfl(lp[s], quad * 4 + r, 16);
      const float inv = 1.0f / li;
      const int qrow = ab * 4096 + qbase + s * 16 + quad * 4 + r;
      bf16* orow = att + qrow * 256 + h * 32;
      orow[l16]      = f2b(o[s][0][r] * inv);
      orow[16 + l16] = f2b(o[s][1][r] * inv);
    }
  }
}

// ---------------------------------------------------------------------------
// Kernel 5: y = att @ Wproj^T + bproj -> fp32 d_out. 2 row-tiles CONCURRENT
// (k0-outer): per K-step 2 A loads + 4 W reads feed 8 MFMA. grid (128,4).
// ---------------------------------------------------------------------------
__global__ __launch_bounds__(256) void proj_mfma(
    const bf16* __restrict__ att, const bf16* __restrict__ wb,
    const float* __restrict__ bp, float* __restrict__ outp) {
  __shared__ bf16 W_lds[64][264];
  const int t = threadIdx.x;
  const int wave = t >> 6, lane = t & 63, quad = lane >> 4, l16 = lane & 15;
  const int colh = blockIdx.y * 64;
  STAGE_W(W_lds, wb + WP_OFF + colh * 256, 256);
  __syncthreads();
  const bf16* ap0 =
      att + ((blockIdx.x * 2) * 64 + wave * 16 + l16) * 256 + quad * 8;
  f32x4 acc[2][4];
  #pragma unroll
  for (int ii = 0; ii < 2; ++ii)
    #pragma unroll
    for (int j = 0; j < 4; ++j) acc[ii][j] = (f32x4){0.f, 0.f, 0.f, 0.f};
  #pragma unroll
  for (int k0 = 0; k0 < 256; k0 += 32) {
    bf16x8 af[2];
    af[0] = *(const bf16x8*)(ap0 + k0);
    af[1] = *(const bf16x8*)(ap0 + 16384 + k0);   // +64 rows
    #pragma unroll
    for (int j = 0; j < 4; ++j) {
      const bf16x8 wf = *(const bf16x8*)&W_lds[j * 16 + l16][k0 + quad * 8];
      acc[0][j] = MFMA(af[0], wf, acc[0][j]);
      acc[1][j] = MFMA(af[1], wf, acc[1][j]);
    }
  }
  #pragma unroll
  for (int ii = 0; ii < 2; ++ii) {
    const int row0 = (blockIdx.x * 2 + ii) * 64 + wave * 16;
    #pragma unroll
    for (int j = 0; j < 4; ++j) {
      const int col = colh + j * 16 + l16;
      const float bv = bp[col];
      #pragma unroll
      for (int r = 0; r < 4; ++r)
        outp[(row0 + quad * 4 + r) * 256 + col] = acc[ii][j][r] + bv;
    }
  }
}

// ---------------------------------------------------------------------------
extern "C" void kernel_launch(void* const* d_in, const int* in_sizes, int n_in,
                              void* d_out, int out_size, void* d_ws, size_t ws_size,
                              hipStream_t stream) {
  const float* x0    = (const float*)d_in[0];
  const float* x1    = (const float*)d_in[1];
  const float* Wq    = (const float*)d_in[2];
  const float* Wkv   = (const float*)d_in[3];
  const float* Wproj = (const float*)d_in[4];
  const float* bproj = (const float*)d_in[5];
  const float* Wsr   = (const float*)d_in[6];
  const float* bsr   = (const float*)d_in[7];
  const float* lnw0  = (const float*)d_in[8];
  const float* lnb0  = (const float*)d_in[9];
  const float* lnw1  = (const float*)d_in[10];
  const float* lnb1  = (const float*)d_in[11];

  // d_out (16 MB): [q bf16 8 MB][xb bf16 8 MB] -> finally y fp32 16 MB.
  // ws (15 MB): att 8 | xsb 2 | kbuf 2 | vbuf_t 2 | wb 1.
  bf16* q_bf   = (bf16*)d_out;
  bf16* xb     = q_bf + 4194304;
  bf16* att_bf = (bf16*)d_ws;
  bf16* xsb    = att_bf + 4194304;
  bf16* kbuf   = xsb + 1048576;
  bf16* vbuf_t = kbuf + 1048576;
  bf16* wb     = vbuf_t + 1048576;
  float* y     = (float*)d_out;

  const dim3 blk(256);
  prep_cvt<<<dim3(1536), blk, 0, stream>>>(x0, x1, xb, Wq, Wkv, Wproj, Wsr, wb);
  qc_mfma<<<dim3(128, 4), blk, 0, stream>>>(xb, wb, bsr, q_bf, xsb);
  kvln_mfma<<<dim3(64, 8), blk, 0, stream>>>(xsb, wb, lnw0, lnb0, lnw1, lnb1,
                                             kbuf, vbuf_t);
  attn_mfma<<<dim3(32, 32), blk, 0, stream>>>(q_bf, kbuf, vbuf_t, att_bf);
  proj_mfma<<<dim3(128, 4), blk, 0, stream>>>(att_bf, wb, bproj, y);
}

// Round 11
// 153.945 us; speedup vs baseline: 1.2019x; 1.0115x over previous
//
#include <hip/hip_runtime.h>
#include <hip/hip_bf16.h>
#include <cstddef>

typedef __hip_bfloat16 bf16;
typedef unsigned int u32;
typedef __attribute__((ext_vector_type(8))) short bf16x8;   // MFMA A/B frag
typedef __attribute__((ext_vector_type(4))) float f32x4;    // MFMA C/D frag
typedef __attribute__((ext_vector_type(4))) short short4v;  // 4x bf16 packed

__device__ __forceinline__ float b2f(bf16 v) { return __bfloat162float(v); }
__device__ __forceinline__ bf16 f2b(float v) { return __float2bfloat16(v); }

#define MFMA(a, b, c) __builtin_amdgcn_mfma_f32_16x16x32_bf16((a), (b), (c), 0, 0, 0)

// Weight layout inside wb (bf16): Wq [0,64K), Wkv [64K,192K), Wp [192K,256K),
// Wsr permuted [256K,512K) with k' = p*256 + c  (p = kh*2+kw).
#define WQ_OFF   0
#define WKV_OFF  65536
#define WP_OFF   196608
#define WSR_OFF  262144

// Async global->LDS, 16 B per lane (wave-uniform LDS base + lane*16).
__device__ __forceinline__ void gload_lds16(const bf16* g, bf16* l) {
  __builtin_amdgcn_global_load_lds(
      (const __attribute__((address_space(1))) u32*)g,
      (__attribute__((address_space(3))) u32*)l, 16, 0, 0);
}

// ---------------------------------------------------------------------------
// Prepass (fused): blocks [0,1024): x0|x1 fp32 -> xb bf16.
//                  blocks [1024,1536): weights fp32 -> wb bf16 (Wsr permuted).
// ---------------------------------------------------------------------------
__global__ __launch_bounds__(256) void prep_cvt(
    const float* __restrict__ x0, const float* __restrict__ x1,
    bf16* __restrict__ xb,
    const float* __restrict__ Wq, const float* __restrict__ Wkv,
    const float* __restrict__ Wp, const float* __restrict__ Wsr,
    bf16* __restrict__ wb) {
  const int t = threadIdx.x;
  if (blockIdx.x < 1024) {
    const int gid = blockIdx.x * 256 + t;             // 262144 threads
    for (int i = gid; i < 1048576; i += 262144) {     // float4 units
      const float4 v = (i < 524288) ? ((const float4*)x0)[i]
                                    : ((const float4*)x1)[i - 524288];
      union { bf16 h[4]; short4v s; } u;
      u.h[0] = f2b(v.x); u.h[1] = f2b(v.y); u.h[2] = f2b(v.z); u.h[3] = f2b(v.w);
      ((short4v*)xb)[i] = u.s;
    }
  } else {
    const int gid = (blockIdx.x - 1024) * 256 + t;    // 131072 threads
    for (int i = gid; i < 524288; i += 131072) {
      float v;
      if (i < WKV_OFF)       v = Wq[i];
      else if (i < WP_OFF)   v = Wkv[i - WKV_OFF];
      else if (i < WSR_OFF)  v = Wp[i - WP_OFF];
      else {
        const int r = i - WSR_OFF;
        const int o = r >> 10, k = r & 1023;
        const int p = k >> 8, c = k & 255;
        v = Wsr[o * 1024 + c * 4 + p];
      }
      wb[i] = f2b(v);
    }
  }
}

// Async W-tile staging: 64 rows x 256 K bf16 (32 KB) into flat LDS with the
// XOR swizzle unit' = row*32 + (c16 ^ (row&7)) applied via the PER-LANE
// GLOBAL SOURCE address (global_load_lds writes LDS linearly: wave-uniform
// base + lane*16 -- rule: swizzle source + read, never the LDS dest).
// Reads use the same XOR; 64 lanes spread over all 8 bank-octets (b128
// floor, conflict-free). Must be followed by __syncthreads() (vmcnt drain).
#define STAGE_WA(W_lds_flat, wgl, ldg)                                       \
  _Pragma("unroll")                                                          \
  for (int uu_ = 0; uu_ < 8; ++uu_) {                                        \
    const int idx_ = uu_ * 256 + t;                                          \
    const int row_ = idx_ >> 5;                                              \
    const int sc_  = (idx_ & 31) ^ (row_ & 7);                               \
    gload_lds16((wgl) + row_ * (ldg) + sc_ * 8,                              \
                (W_lds_flat) + (uu_ * 256 + (t & ~63)) * 8);                 \
  }

// Swizzled W read: fragment at (row = j16, col elems cbase + quad*8).
#define WREAD(W_lds_flat, j16, cbase)                                        \
  (*(const bf16x8*)&(W_lds_flat)[((j16) * 32 +                               \
      ((((cbase) >> 3) + quad) ^ (l16 & 7))) * 8])

// ---------------------------------------------------------------------------
// Kernel 2 (fused): blocks x<64:  conv as 4 p-passes of 256-K MFMA GEMM
//                                 (scheduled FIRST: long blocks, no tail).
//                   blocks x>=64: q = (xb @ Wq^T) * scale' -> bf16,
//                                 4 row-tiles concurrent, k0-outer.
// grid (128,4) = 512 blocks. scale' folds log2(e) -> raw v_exp_f32.
// ---------------------------------------------------------------------------
__global__ __launch_bounds__(256) void qc_mfma(
    const bf16* __restrict__ xb, const bf16* __restrict__ wb,
    const float* __restrict__ bsr, bf16* __restrict__ q,
    bf16* __restrict__ xsb) {
  __shared__ bf16 W_lds[16384];   // 64 x 256, swizzled units (32 KB)
  const int t = threadIdx.x;
  const int wave = t >> 6, lane = t & 63, quad = lane >> 4, l16 = lane & 15;
  const int colh = blockIdx.y * 64;

  if (blockIdx.x < 64) {
    // ---- conv body ----
    const int bx = blockIdx.x;
    const int row0 = bx * 64 + wave * 16;
    const int mrow = row0 + l16;
    const int ab = mrow >> 10;
    const int m = mrow & 1023;
    const int mi_ = m >> 5, mj = m & 31;
    f32x4 acc[4];
    #pragma unroll
    for (int j = 0; j < 4; ++j) acc[j] = (f32x4){0.f, 0.f, 0.f, 0.f};
    for (int p = 0; p < 4; ++p) {
      __syncthreads();   // protect previous pass's W_lds reads
      STAGE_WA(W_lds, wb + WSR_OFF + colh * 1024 + p * 256, 1024);
      __syncthreads();
      const int n = (2 * mi_ + (p >> 1)) * 64 + 2 * mj + (p & 1);
      const bf16* ap = xb + (ab * 4096 + n) * 256 + quad * 8;
      #pragma unroll
      for (int c0 = 0; c0 < 256; c0 += 32) {
        const bf16x8 af = *(const bf16x8*)(ap + c0);
        #pragma unroll
        for (int j = 0; j < 4; ++j) {
          const bf16x8 wf = WREAD(W_lds, j * 16 + l16, c0);
          acc[j] = MFMA(af, wf, acc[j]);
        }
      }
    }
    #pragma unroll
    for (int j = 0; j < 4; ++j) {
      const int col = colh + j * 16 + l16;
      const float bv = bsr[col];
      #pragma unroll
      for (int r = 0; r < 4; ++r)
        xsb[(row0 + quad * 4 + r) * 256 + col] = f2b(acc[j][r] + bv);
    }
  } else {
    // ---- q-projection: 4 row-tiles concurrent, k0-outer ----
    const int idx = blockIdx.x - 64;          // 0..63
    STAGE_WA(W_lds, wb + WQ_OFF + colh * 256, 256);
    __syncthreads();
    const bf16* ap0 =
        xb + ((idx * 4) * 64 + wave * 16 + l16) * 256 + quad * 8;
    f32x4 acc[4][4];                          // [row-tile ii][col j]
    #pragma unroll
    for (int ii = 0; ii < 4; ++ii)
      #pragma unroll
      for (int j = 0; j < 4; ++j) acc[ii][j] = (f32x4){0.f, 0.f, 0.f, 0.f};
    #pragma unroll
    for (int k0 = 0; k0 < 256; k0 += 32) {
      bf16x8 af[4];
      #pragma unroll
      for (int ii = 0; ii < 4; ++ii)
        af[ii] = *(const bf16x8*)(ap0 + ii * 16384 + k0);   // +64 rows each
      #pragma unroll
      for (int j = 0; j < 4; ++j) {
        const bf16x8 wf = WREAD(W_lds, j * 16 + l16, k0);
        #pragma unroll
        for (int ii = 0; ii < 4; ++ii)
          acc[ii][j] = MFMA(af[ii], wf, acc[ii][j]);
      }
    }
    const float scale = 0.2550348572f;  // log2(e)/sqrt(32)
    #pragma unroll
    for (int ii = 0; ii < 4; ++ii) {
      const int row0 = (idx * 4 + ii) * 64 + wave * 16;
      #pragma unroll
      for (int j = 0; j < 4; ++j)
        #pragma unroll
        for (int r = 0; r < 4; ++r)
          q[(row0 + quad * 4 + r) * 256 + colh + j * 16 + l16] =
              f2b(acc[ii][j][r] * scale);
    }
  }
}

// ---------------------------------------------------------------------------
// Kernel 3 (fused LN + kv): LayerNorm over C=256 in-register (quad-reduce
// via shfl_xor 16/32), then kv = ln(xsb) @ Wkv^T.
// K-half -> kbuf [abh][m][d]; V-half -> vbuf_t [abh][d][m'] with the bit
// permutation m' = (m&~63) | km(m&63),
//   km(j) = (j&32) | ((j&12)<<1) | ((j&16)>>2) | (j&3),
// so the swapped-QK attention's P fragments are lane-local. grid (64, 8).
// ---------------------------------------------------------------------------
__global__ __launch_bounds__(256) void kvln_mfma(
    const bf16* __restrict__ xsb, const bf16* __restrict__ wb,
    const float* __restrict__ w0, const float* __restrict__ b0,
    const float* __restrict__ w1, const float* __restrict__ b1,
    bf16* __restrict__ kbuf, bf16* __restrict__ vbuf_t) {
  __shared__ bf16 W_lds[16384];
  __shared__ float lnw[256], lnb[256];
  const int t = threadIdx.x;
  const int wave = t >> 6, lane = t & 63, quad = lane >> 4, l16 = lane & 15;
  const int row0 = blockIdx.x * 64 + wave * 16;
  const int colh = blockIdx.y * 64;     // 0..448 over O=512
  const int a = (blockIdx.x * 64) >> 11;   // block-uniform LN param select
  lnw[t] = a ? w1[t] : w0[t];
  lnb[t] = a ? b1[t] : b0[t];
  STAGE_WA(W_lds, wb + WKV_OFF + colh * 256, 256);
  __syncthreads();

  const bf16* ap = xsb + (row0 + l16) * 256 + quad * 8;
  bf16x8 af[8];
  float sum = 0.f, ss = 0.f;
  #pragma unroll
  for (int i = 0; i < 8; ++i) {
    af[i] = *(const bf16x8*)(ap + i * 32);
    #pragma unroll
    for (int e = 0; e < 8; ++e) {
      const float x = b2f(((bf16*)&af[i])[e]);
      sum += x; ss += x * x;
    }
  }
  sum += __shfl_xor(sum, 16, 64); sum += __shfl_xor(sum, 32, 64);
  ss  += __shfl_xor(ss, 16, 64);  ss  += __shfl_xor(ss, 32, 64);
  const float mu = sum * (1.0f / 256.0f);
  const float var = ss * (1.0f / 256.0f) - mu * mu;
  const float rstd = rsqrtf(var + 1e-5f);
  #pragma unroll
  for (int i = 0; i < 8; ++i) {
    const int cb = i * 32 + quad * 8;
    union { bf16 h[8]; bf16x8 v; } u;
    #pragma unroll
    for (int e = 0; e < 8; ++e) {
      const float x = b2f(((bf16*)&af[i])[e]);
      u.h[e] = f2b((x - mu) * rstd * lnw[cb + e] + lnb[cb + e]);
    }
    af[i] = u.v;
  }

  f32x4 acc[4];
  #pragma unroll
  for (int j = 0; j < 4; ++j) acc[j] = (f32x4){0.f, 0.f, 0.f, 0.f};
  #pragma unroll
  for (int i = 0; i < 8; ++i) {
    #pragma unroll
    for (int j = 0; j < 4; ++j) {
      const bf16x8 wf = WREAD(W_lds, j * 16 + l16, i * 32);
      acc[j] = MFMA(af[i], wf, acc[j]);
    }
  }
  #pragma unroll
  for (int j = 0; j < 4; ++j) {
    const int o = colh + j * 16 + l16;   // 0..511
    #pragma unroll
    for (int r = 0; r < 4; ++r) {
      const int row = row0 + quad * 4 + r;
      const int m = row & 1023;
      const bf16 val = f2b(acc[j][r]);
      if (o < 256) {
        const int h = o >> 5, d = o & 31;
        kbuf[((row >> 10) * 8 + h) * 32768 + m * 32 + d] = val;
      } else {
        const int o2 = o - 256;
        const int h = o2 >> 5, d = o2 & 31;
        const int rr = m & 63;
        const int mp = (m & ~63) | (rr & 32) | ((rr & 12) << 1) |
                       ((rr & 16) >> 2) | (rr & 3);
        vbuf_t[((row >> 10) * 8 + h) * 32768 + d * 1024 + mp] = val;
      }
    }
  }
}

// ---------------------------------------------------------------------------
// Kernel 4: MFMA flash attention — the PROVEN round-2/6 structure verbatim:
// LDS-staged K/V, double-buffered, per-64-key tiles, swapped QK^T
// (S^T = K x Q) with lane-local in-register P -> PV fragments.
// q pre-scaled by log2(e)/sqrt(d) -> raw v_exp_f32. Best of 4 measured
// attention structures.
// ---------------------------------------------------------------------------
__global__ __launch_bounds__(256) void attn_mfma(
    const bf16* __restrict__ q, const bf16* __restrict__ kbuf,
    const bf16* __restrict__ vbuf_t, bf16* __restrict__ att) {
  const int abh = blockIdx.y;
  const int ab = abh >> 3;
  const int h = abh & 7;
  const int t = threadIdx.x;
  const int lane = t & 63, quad = lane >> 4, l16 = lane & 15;
  const int qbase = blockIdx.x * 128 + (t >> 6) * 32;

  __shared__ bf16 KT[2][2048];
  __shared__ bf16 VT[2][2048];

  const bf16* kb = kbuf + abh * 32768;
  const bf16* vb = vbuf_t + abh * 32768;

  const int kg = (t >> 6) * 512 + ((t >> 2) & 15) * 32 + (t & 3) * 8;
  const int vg_row = (t >> 7) * 16 + ((t >> 3) & 15);
  const int vg_col = ((t >> 2) & 1) * 32 + (t & 3) * 8;

  bf16x8 qf[2];
  #pragma unroll
  for (int s = 0; s < 2; ++s)
    qf[s] = *(const bf16x8*)(
        q + (ab * 4096 + qbase + s * 16 + l16) * 256 + h * 32 + quad * 8);

  {
    const bf16x8 kr = *(const bf16x8*)(kb + kg);
    const bf16x8 vr = *(const bf16x8*)(vb + vg_row * 1024 + vg_col);
    *(bf16x8*)&KT[0][t * 8] = kr;
    *(bf16x8*)&VT[0][t * 8] = vr;
  }
  __syncthreads();

  f32x4 o[2][2];
  float lp[2] = {0.f, 0.f};
  #pragma unroll
  for (int s = 0; s < 2; ++s) {
    o[s][0] = (f32x4){0.f, 0.f, 0.f, 0.f};
    o[s][1] = (f32x4){0.f, 0.f, 0.f, 0.f};
  }
  const f32x4 zero = {0.f, 0.f, 0.f, 0.f};

  for (int kt = 0; kt < 16; ++kt) {
    const int cur = kt & 1;
    bf16x8 kr, vr;
    const bool pf = (kt + 1 < 16);
    if (pf) {
      const int nk0 = (kt + 1) * 64;
      kr = *(const bf16x8*)(kb + nk0 * 32 + kg);
      vr = *(const bf16x8*)(vb + vg_row * 1024 + nk0 + vg_col);
    }
    // S^T[key][q]: A = K-frag (row=key), B = Q-frag (col=q=l16).
    f32x4 S[2][4];
    #pragma unroll
    for (int tt = 0; tt < 4; ++tt) {
      const bf16x8 kf =
          *(const bf16x8*)&KT[cur][(tt * 64 + l16 * 4 + quad) * 8];
      S[0][tt] = MFMA(kf, qf[0], zero);
      S[1][tt] = MFMA(kf, qf[1], zero);
    }
    // In-register softmax numerator + lane-local PV A-fragments.
    bf16x8 pa[2][2];
    #pragma unroll
    for (int s = 0; s < 2; ++s) {
      float p[4][4];
      float acc = 0.f;
      #pragma unroll
      for (int tt = 0; tt < 4; ++tt)
        #pragma unroll
        for (int r = 0; r < 4; ++r) {
          p[tt][r] = __builtin_amdgcn_exp2f(S[s][tt][r]);
          acc += p[tt][r];
        }
      lp[s] += acc;
      #pragma unroll
      for (int c2 = 0; c2 < 2; ++c2) {
        union { __hip_bfloat162 h2[4]; bf16x8 v; } u;
        u.h2[0] = __float22bfloat162_rn(float2{p[c2 * 2][0], p[c2 * 2][1]});
        u.h2[1] = __float22bfloat162_rn(float2{p[c2 * 2][2], p[c2 * 2][3]});
        u.h2[2] = __float22bfloat162_rn(float2{p[c2 * 2 + 1][0], p[c2 * 2 + 1][1]});
        u.h2[3] = __float22bfloat162_rn(float2{p[c2 * 2 + 1][2], p[c2 * 2 + 1][3]});
        pa[s][c2] = u.v;
      }
    }
    #pragma unroll
    for (int c2 = 0; c2 < 2; ++c2) {
      #pragma unroll
      for (int dh = 0; dh < 2; ++dh) {
        const bf16x8 vf = *(const bf16x8*)&VT[cur]
            [(dh * 128 + l16 * 8 + c2 * 4 + quad) * 8];
        o[0][dh] = MFMA(pa[0][c2], vf, o[0][dh]);
        o[1][dh] = MFMA(pa[1][c2], vf, o[1][dh]);
      }
    }
    if (pf) {
      *(bf16x8*)&KT[cur ^ 1][t * 8] = kr;
      *(bf16x8*)&VT[cur ^ 1][t * 8] = vr;
    }
    __syncthreads();
  }
  // Denominator: sum across quads (lane ^16, ^32), broadcast, normalize.
  #pragma unroll
  for (int s = 0; s < 2; ++s) {
    lp[s] += __shfl_xor(lp[s], 16, 64);
    lp[s] += __shfl_xor(lp[s], 32, 64);
  }
  #pragma unroll
  for (int s = 0; s < 2; ++s) {
    #pragma unroll
    for (int r = 0; r < 4; ++r) {
      const float li = __shfl(lp[s], quad * 4 + r, 16);
      const float inv = 1.0f / li;
      const int qrow = ab * 4096 + qbase + s * 16 + quad * 4 + r;
      bf16* orow = att + qrow * 256 + h * 32;
      orow[l16]      = f2b(o[s][0][r] * inv);
      orow[16 + l16] = f2b(o[s][1][r] * inv);
    }
  }
}

// ---------------------------------------------------------------------------
// Kernel 5: y = att @ Wproj^T + bproj -> fp32 d_out. 2 row-tiles CONCURRENT
// (k0-outer). grid (128,4).
// ---------------------------------------------------------------------------
__global__ __launch_bounds__(256) void proj_mfma(
    const bf16* __restrict__ att, const bf16* __restrict__ wb,
    const float* __restrict__ bp, float* __restrict__ outp) {
  __shared__ bf16 W_lds[16384];
  const int t = threadIdx.x;
  const int wave = t >> 6, lane = t & 63, quad = lane >> 4, l16 = lane & 15;
  const int colh = blockIdx.y * 64;
  STAGE_WA(W_lds, wb + WP_OFF + colh * 256, 256);
  __syncthreads();
  const bf16* ap0 =
      att + ((blockIdx.x * 2) * 64 + wave * 16 + l16) * 256 + quad * 8;
  f32x4 acc[2][4];
  #pragma unroll
  for (int ii = 0; ii < 2; ++ii)
    #pragma unroll
    for (int j = 0; j < 4; ++j) acc[ii][j] = (f32x4){0.f, 0.f, 0.f, 0.f};
  #pragma unroll
  for (int k0 = 0; k0 < 256; k0 += 32) {
    bf16x8 af[2];
    af[0] = *(const bf16x8*)(ap0 + k0);
    af[1] = *(const bf16x8*)(ap0 + 16384 + k0);   // +64 rows
    #pragma unroll
    for (int j = 0; j < 4; ++j) {
      const bf16x8 wf = WREAD(W_lds, j * 16 + l16, k0);
      acc[0][j] = MFMA(af[0], wf, acc[0][j]);
      acc[1][j] = MFMA(af[1], wf, acc[1][j]);
    }
  }
  #pragma unroll
  for (int ii = 0; ii < 2; ++ii) {
    const int row0 = (blockIdx.x * 2 + ii) * 64 + wave * 16;
    #pragma unroll
    for (int j = 0; j < 4; ++j) {
      const int col = colh + j * 16 + l16;
      const float bv = bp[col];
      #pragma unroll
      for (int r = 0; r < 4; ++r)
        outp[(row0 + quad * 4 + r) * 256 + col] = acc[ii][j][r] + bv;
    }
  }
}

// ---------------------------------------------------------------------------
extern "C" void kernel_launch(void* const* d_in, const int* in_sizes, int n_in,
                              void* d_out, int out_size, void* d_ws, size_t ws_size,
                              hipStream_t stream) {
  const float* x0    = (const float*)d_in[0];
  const float* x1    = (const float*)d_in[1];
  const float* Wq    = (const float*)d_in[2];
  const float* Wkv   = (const float*)d_in[3];
  const float* Wproj = (const float*)d_in[4];
  const float* bproj = (const float*)d_in[5];
  const float* Wsr   = (const float*)d_in[6];
  const float* bsr   = (const float*)d_in[7];
  const float* lnw0  = (const float*)d_in[8];
  const float* lnb0  = (const float*)d_in[9];
  const float* lnw1  = (const float*)d_in[10];
  const float* lnb1  = (const float*)d_in[11];

  // d_out (16 MB): [q bf16 8 MB][xb bf16 8 MB] -> finally y fp32 16 MB.
  // ws (15 MB): att 8 | xsb 2 | kbuf 2 | vbuf_t 2 | wb 1.
  bf16* q_bf   = (bf16*)d_out;
  bf16* xb     = q_bf + 4194304;
  bf16* att_bf = (bf16*)d_ws;
  bf16* xsb    = att_bf + 4194304;
  bf16* kbuf   = xsb + 1048576;
  bf16* vbuf_t = kbuf + 1048576;
  bf16* wb     = vbuf_t + 1048576;
  float* y     = (float*)d_out;

  const dim3 blk(256);
  prep_cvt<<<dim3(1536), blk, 0, stream>>>(x0, x1, xb, Wq, Wkv, Wproj, Wsr, wb);
  qc_mfma<<<dim3(128, 4), blk, 0, stream>>>(xb, wb, bsr, q_bf, xsb);
  kvln_mfma<<<dim3(64, 8), blk, 0, stream>>>(xsb, wb, lnw0, lnb0, lnw1, lnb1,
                                             kbuf, vbuf_t);
  attn_mfma<<<dim3(32, 32), blk, 0, stream>>>(q_bf, kbuf, vbuf_t, att_bf);
  proj_mfma<<<dim3(128, 4), blk, 0, stream>>>(att_bf, wb, bproj, y);
}